// Round 6
// baseline (322.956 us; speedup 1.0000x reference)
//
#include <hip/hip_runtime.h>

// AliasFreeActivation fused kernel, round 6 (= round 5 with B odd-group fix):
//  - all phases shaped for max active lanes (B: 247x6-row tasks, C/D: 256 thr)
//  - block-uniform edge flag: interior blocks skip clamps/bounds checks
//  - leaky as select-multiplier
//  - no xt staging (A reads global direct), bias fold, 32.2KB LDS
//
// Math (verified rounds 1-4):
//  A  h-up:   t1[r][u]=sum_t f[k0+4t]*xw[bb-t], u=8ug+du, k0=(du+1)&3,
//             bb=((du+25-k0)>>2)-1, window x cols [2ug,2ug+7]. No bias.
//  B  v-up:   act[v][:] = sum_t f[k0+4t]*w[lb+5-t][:] + b*s[k0u]*s[k0],
//             base(v)=5+((v+1)>>2), k0=(v+1)&3; leaky*sqrt2.
//             6-row groups g, v=6g+dv, rbase=3*(g>>1)+(g&1), w[m]=t1[rbase+m],
//             lb = base(v)-rbase-5.
//             even g (v0=12h, rbase=3h):   k0=(dv+1)&3={1,2,3,0,1,2},
//                                          lb=((dv+1)>>2)={0,0,0,1,1,1}
//             odd  g (v0=12h+6,rbase=3h+1):k0=(dv+3)&3={3,0,1,2,3,0},
//                                          lb=((dv+7)>>2)-1={0,1,1,1,1,2}
//  C  h-down: t2t[o][v]=sum_k g[k]*act[v][2o+11-k], o=8otg+i.
//  D  v-down: out[4g+dv][ox]=sum_k g[k]*t2t[ox][8g+2dv+11-k].
//
// LDS (words): act 74x76 @0 | t1 26x84 @5624 | t2t 32x76 @5624 (aliases t1).
// Total 8056 w = 32224 B. t2t cols 74,75 garbage, never used (D max v=73).

typedef float f4 __attribute__((ext_vector_type(4)));

#define ACTS4   19
#define T1OFF4  1406
#define T1S4    21
#define T2TOFF  5624
#define T2TS    76
#define LDSW    8056

__global__ __launch_bounds__(256, 4) void afa_kernel(
    const float* __restrict__ x, const float* __restrict__ bias,
    const float* __restrict__ fup, const float* __restrict__ fdn,
    float* __restrict__ out)
{
    __shared__ __align__(16) float lds[LDSW];
    f4* lds4 = (f4*)lds;

    const int tid   = threadIdx.x;
    const int blk   = blockIdx.x;
    const int plane = blk >> 6;
    const int tile  = blk & 63;
    const int ty = tile >> 3, tx = tile & 7;
    const bool edge = (tx == 7) || (ty == 7);

    float fr[24], gr[12];
    #pragma unroll
    for (int i = 0; i < 24; ++i) fr[i] = fup[i];
    #pragma unroll
    for (int i = 0; i < 12; ++i) gr[i] = fdn[i];

    // bias fold: up(x+b) = up(x) + b*s[k0u]*s[k0v], s[p]=sum_t f[p+4t]
    const float s0 = fr[0] + fr[4] + fr[8]  + fr[12] + fr[16] + fr[20];
    const float s1 = fr[1] + fr[5] + fr[9]  + fr[13] + fr[17] + fr[21];
    const float s2 = fr[2] + fr[6] + fr[10] + fr[14] + fr[18] + fr[22];
    const float s3 = fr[3] + fr[7] + fr[11] + fr[15] + fr[19] + fr[23];
    const float b  = bias[plane & 255];
    const f4 su4 = {s1, s2, s3, s0};              // s[(cc+1)&3]
    f4 bc[4];
    bc[0] = su4 * (b * s0);
    bc[1] = su4 * (b * s1);
    bc[2] = su4 * (b * s2);
    bc[3] = su4 * (b * s3);

    const int iy_base = 16 * ty + 1;
    const int ix_base = 16 * tx + 1;
    const float* xp = x + (size_t)plane * (128 * 128);

    // ---- A: horizontal upsample, direct global reads -> t1 (26 x 80) ----
    for (int task = tid; task < 260; task += 256) {
        const int r = task / 10, ug = task - r * 10;
        float xw[8];
        if (!edge) {
            const float* row = xp + (iy_base + r) * 128 + (ix_base + 2 * ug);
            #pragma unroll
            for (int m = 0; m < 8; ++m) xw[m] = row[m];
        } else {
            const int iy = min(iy_base + r, 127);
            const float* row = xp + iy * 128;
            const int ix0 = ix_base + 2 * ug;
            #pragma unroll
            for (int m = 0; m < 8; ++m) xw[m] = row[min(ix0 + m, 127)];
        }
        f4 res0, res1;
        #pragma unroll
        for (int du = 0; du < 8; ++du) {
            const int k0 = (du + 1) & 3;
            const int bb = ((du + 25 - k0) >> 2) - 1;
            float acc = 0.f;
            #pragma unroll
            for (int t = 0; t < 6; ++t) acc += fr[k0 + 4 * t] * xw[bb - t];
            if (du < 4) res0[du] = acc; else res1[du - 4] = acc;
        }
        lds4[T1OFF4 + r * T1S4 + 2 * ug]     = res0;
        lds4[T1OFF4 + r * T1S4 + 2 * ug + 1] = res1;
    }
    __syncthreads();

    // ---- B: vertical upsample + bias + leaky*sqrt2 -> act (74 x 76) ----
    if (tid < 247) {
        const int g = tid / 19, ut = tid - g * 19;
        const int rbase = 3 * (g >> 1) + (g & 1);
        const int v0 = 6 * g;
        f4 w[8];
        #pragma unroll
        for (int m = 0; m < 8; ++m)
            w[m] = lds4[T1OFF4 + (rbase + m) * T1S4 + ut];

#define BROW(dvC, k0C, lbC)                                               \
        {                                                                 \
            const int v = v0 + (dvC);                                     \
            if ((dvC) < 2 || v < 74) {                                    \
                f4 acc = bc[k0C];                                         \
                acc += fr[(k0C) +  0] * w[(lbC) + 5];                     \
                acc += fr[(k0C) +  4] * w[(lbC) + 4];                     \
                acc += fr[(k0C) +  8] * w[(lbC) + 3];                     \
                acc += fr[(k0C) + 12] * w[(lbC) + 2];                     \
                acc += fr[(k0C) + 16] * w[(lbC) + 1];                     \
                acc += fr[(k0C) + 20] * w[(lbC) + 0];                     \
                f4 r2;                                                    \
                _Pragma("unroll")                                         \
                for (int cc = 0; cc < 4; ++cc) {                          \
                    float vv = acc[cc];                                   \
                    r2[cc] = vv * (vv >= 0.f ? 1.4142135623730951f        \
                                             : 0.28284271247461906f);    \
                }                                                         \
                lds4[v * ACTS4 + ut] = r2;                                \
            }                                                             \
        }

        if ((g & 1) == 0) {
            // k0=(dv+1)&3, lb=(dv+1)>>2
            BROW(0, 1, 0) BROW(1, 2, 0) BROW(2, 3, 0)
            BROW(3, 0, 1) BROW(4, 1, 1) BROW(5, 2, 1)
        } else {
            // k0=(dv+3)&3, lb=((dv+7)>>2)-1
            BROW(0, 3, 0) BROW(1, 0, 1) BROW(2, 1, 1)
            BROW(3, 2, 1) BROW(4, 3, 1) BROW(5, 0, 2)
        }
#undef BROW
    }
    __syncthreads();

    // ---- C: horizontal downsample -> t2t[o][v] (transposed) ----
    {
        // batch 1: rows 0..63, all 256 threads
        const int v = tid & 63, otg = tid >> 6;
        {
            union { f4 q[7]; float s[28]; } aw;
            #pragma unroll
            for (int j = 0; j < 7; ++j)
                aw.q[j] = lds4[v * ACTS4 + 4 * otg + j];
            #pragma unroll
            for (int i = 0; i < 8; ++i) {
                float acc = 0.f;
                #pragma unroll
                for (int k = 0; k < 12; ++k) acc += gr[k] * aw.s[2 * i + 11 - k];
                lds[T2TOFF + (8 * otg + i) * T2TS + v] = acc;
            }
        }
        // batch 2: rows 64..73
        if (tid < 64) {
            const int otg2 = tid >> 4, vr = tid & 15;
            if (vr < 10) {
                const int v2 = 64 + vr;
                union { f4 q[7]; float s[28]; } aw;
                #pragma unroll
                for (int j = 0; j < 7; ++j)
                    aw.q[j] = lds4[v2 * ACTS4 + 4 * otg2 + j];
                #pragma unroll
                for (int i = 0; i < 8; ++i) {
                    float acc = 0.f;
                    #pragma unroll
                    for (int k = 0; k < 12; ++k) acc += gr[k] * aw.s[2 * i + 11 - k];
                    lds[T2TOFF + (8 * otg2 + i) * T2TS + v2] = acc;
                }
            }
        }
    }
    __syncthreads();

    // ---- D: vertical downsample, 4 rows x 1 col/thread -> global ----
    {
        const int oy0 = ty * 32, ox0 = tx * 32;
        float* op = out + (size_t)plane * (236 * 236);
        const int ox = tid & 31, g = tid >> 5;
        union { f4 q[5]; float s[20]; } cw;
        #pragma unroll
        for (int j = 0; j < 5; ++j)
            cw.q[j] = lds4[T1OFF4 + ox * ACTS4 + 2 * g + j];
        const int oxg = ox0 + ox;
        if (!edge) {
            #pragma unroll
            for (int dv = 0; dv < 4; ++dv) {
                float acc = 0.f;
                #pragma unroll
                for (int k = 0; k < 12; ++k) acc += gr[k] * cw.s[2 * dv + 11 - k];
                op[(oy0 + 4 * g + dv) * 236 + oxg] = acc;
            }
        } else {
            #pragma unroll
            for (int dv = 0; dv < 4; ++dv) {
                float acc = 0.f;
                #pragma unroll
                for (int k = 0; k < 12; ++k) acc += gr[k] * cw.s[2 * dv + 11 - k];
                const int oy = oy0 + 4 * g + dv;
                if (oy < 236 && oxg < 236) op[oy * 236 + oxg] = acc;
            }
        }
    }
}

extern "C" void kernel_launch(void* const* d_in, const int* in_sizes, int n_in,
                              void* d_out, int out_size, void* d_ws, size_t ws_size,
                              hipStream_t stream) {
    const float* x    = (const float*)d_in[0];
    const float* bias = (const float*)d_in[1];
    const float* fup  = (const float*)d_in[2];
    const float* fdn  = (const float*)d_in[3];
    float* out = (float*)d_out;

    dim3 grid(1024 * 64);
    dim3 block(256);
    afa_kernel<<<grid, block, 0, stream>>>(x, bias, fup, fdn, out);
}

// Round 7
// 273.659 us; speedup vs baseline: 1.1801x; 1.1801x over previous
//
#include <hip/hip_runtime.h>

// AliasFreeActivation fused kernel, round 7:
//  - B back to 190x8-row shape (r4-verified loop, bias fold kept)
//  - __launch_bounds__(256,5): LDS 32.2KB allows 5 blocks/CU (was capped at 4)
//  - direct-global A with block-uniform edge flag; r3-shape C/D (256 threads)
//
// Math (verified rounds 1-6):
//  A  h-up:   t1[r][u]=sum_t f[k0+4t]*xw[bb-t], u=8ug+du, k0=(du+1)&3,
//             bb=((du+25-k0)>>2)-1, window x cols [2ug,2ug+7]. No bias.
//  B  v-up:   act[v][:]=sum_t f[k0+4t]*w[bb-t][:]+bc[k0]; v=8vt8+dv (<74),
//             k0=(dv+1)&3, bb=5+((dv+1)>>2), w[m]=t1[2vt8+m]; leaky*sqrt2.
//  C  h-down: t2t[o][v]=sum_k g[k]*act[v][2o+11-k], o=8otg+i.
//  D  v-down: out[4g+dv][ox]=sum_k g[k]*t2t[ox][8g+2dv+11-k].
//
// LDS (words): act 74x76 @0 | t1 26x84 @5624 | t2t 32x76 @5624 (aliases t1).
// Total 8056 w = 32224 B -> 5 blocks/CU. t2t cols 74,75 garbage, never used.

typedef float f4 __attribute__((ext_vector_type(4)));

#define ACTS4   19
#define T1OFF4  1406
#define T1S4    21
#define T2TOFF  5624
#define T2TS    76
#define LDSW    8056

__global__ __launch_bounds__(256, 5) void afa_kernel(
    const float* __restrict__ x, const float* __restrict__ bias,
    const float* __restrict__ fup, const float* __restrict__ fdn,
    float* __restrict__ out)
{
    __shared__ __align__(16) float lds[LDSW];
    f4* lds4 = (f4*)lds;

    const int tid   = threadIdx.x;
    const int blk   = blockIdx.x;
    const int plane = blk >> 6;
    const int tile  = blk & 63;
    const int ty = tile >> 3, tx = tile & 7;
    const bool edge = (tx == 7) || (ty == 7);

    float fr[24], gr[12];
    #pragma unroll
    for (int i = 0; i < 24; ++i) fr[i] = fup[i];
    #pragma unroll
    for (int i = 0; i < 12; ++i) gr[i] = fdn[i];

    // bias fold: up(x+b) = up(x) + b*s[k0u]*s[k0v], s[p]=sum_t f[p+4t]
    const float s0 = fr[0] + fr[4] + fr[8]  + fr[12] + fr[16] + fr[20];
    const float s1 = fr[1] + fr[5] + fr[9]  + fr[13] + fr[17] + fr[21];
    const float s2 = fr[2] + fr[6] + fr[10] + fr[14] + fr[18] + fr[22];
    const float s3 = fr[3] + fr[7] + fr[11] + fr[15] + fr[19] + fr[23];
    const float b  = bias[plane & 255];
    const f4 su4 = {s1, s2, s3, s0};              // s[(cc+1)&3]
    f4 bc[4];
    bc[0] = su4 * (b * s0);
    bc[1] = su4 * (b * s1);
    bc[2] = su4 * (b * s2);
    bc[3] = su4 * (b * s3);

    const int iy_base = 16 * ty + 1;
    const int ix_base = 16 * tx + 1;
    const float* xp = x + (size_t)plane * (128 * 128);

    // ---- A: horizontal upsample, direct global reads -> t1 (26 x 80) ----
    for (int task = tid; task < 260; task += 256) {
        const int r = task / 10, ug = task - r * 10;
        float xw[8];
        if (!edge) {
            const float* row = xp + (iy_base + r) * 128 + (ix_base + 2 * ug);
            #pragma unroll
            for (int m = 0; m < 8; ++m) xw[m] = row[m];
        } else {
            const int iy = min(iy_base + r, 127);
            const float* row = xp + iy * 128;
            const int ix0 = ix_base + 2 * ug;
            #pragma unroll
            for (int m = 0; m < 8; ++m) xw[m] = row[min(ix0 + m, 127)];
        }
        f4 res0, res1;
        #pragma unroll
        for (int du = 0; du < 8; ++du) {
            const int k0 = (du + 1) & 3;
            const int bb = ((du + 25 - k0) >> 2) - 1;
            float acc = 0.f;
            #pragma unroll
            for (int t = 0; t < 6; ++t) acc += fr[k0 + 4 * t] * xw[bb - t];
            if (du < 4) res0[du] = acc; else res1[du - 4] = acc;
        }
        lds4[T1OFF4 + r * T1S4 + 2 * ug]     = res0;
        lds4[T1OFF4 + r * T1S4 + 2 * ug + 1] = res1;
    }
    __syncthreads();

    // ---- B: vertical upsample + bias + leaky*sqrt2 -> act (74 x 76) ----
    if (tid < 190) {
        const int vt8 = tid / 19, ut = tid - vt8 * 19;
        f4 w[8];
        #pragma unroll
        for (int m = 0; m < 8; ++m)
            w[m] = lds4[T1OFF4 + (2 * vt8 + m) * T1S4 + ut];
        #pragma unroll
        for (int dv = 0; dv < 8; ++dv) {
            const int row = 8 * vt8 + dv;
            if (row < 74) {
                const int k0 = (dv + 1) & 3;
                const int bb = 5 + ((dv + 1) >> 2);
                f4 acc = bc[k0];
                #pragma unroll
                for (int t = 0; t < 6; ++t) acc += fr[k0 + 4 * t] * w[bb - t];
                f4 r2;
                #pragma unroll
                for (int cc = 0; cc < 4; ++cc) {
                    float vv = acc[cc];
                    r2[cc] = vv * (vv >= 0.f ? 1.4142135623730951f
                                             : 0.28284271247461906f);
                }
                lds4[row * ACTS4 + ut] = r2;
            }
        }
    }
    __syncthreads();

    // ---- C: horizontal downsample -> t2t[o][v] (transposed) ----
    {
        // batch 1: rows 0..63, all 256 threads
        const int v = tid & 63, otg = tid >> 6;
        {
            union { f4 q[7]; float s[28]; } aw;
            #pragma unroll
            for (int j = 0; j < 7; ++j)
                aw.q[j] = lds4[v * ACTS4 + 4 * otg + j];
            #pragma unroll
            for (int i = 0; i < 8; ++i) {
                float acc = 0.f;
                #pragma unroll
                for (int k = 0; k < 12; ++k) acc += gr[k] * aw.s[2 * i + 11 - k];
                lds[T2TOFF + (8 * otg + i) * T2TS + v] = acc;
            }
        }
        // batch 2: rows 64..73
        if (tid < 64) {
            const int otg2 = tid >> 4, vr = tid & 15;
            if (vr < 10) {
                const int v2 = 64 + vr;
                union { f4 q[7]; float s[28]; } aw;
                #pragma unroll
                for (int j = 0; j < 7; ++j)
                    aw.q[j] = lds4[v2 * ACTS4 + 4 * otg2 + j];
                #pragma unroll
                for (int i = 0; i < 8; ++i) {
                    float acc = 0.f;
                    #pragma unroll
                    for (int k = 0; k < 12; ++k) acc += gr[k] * aw.s[2 * i + 11 - k];
                    lds[T2TOFF + (8 * otg2 + i) * T2TS + v2] = acc;
                }
            }
        }
    }
    __syncthreads();

    // ---- D: vertical downsample, 4 rows x 1 col/thread -> global ----
    {
        const int oy0 = ty * 32, ox0 = tx * 32;
        float* op = out + (size_t)plane * (236 * 236);
        const int ox = tid & 31, g = tid >> 5;
        union { f4 q[5]; float s[20]; } cw;
        #pragma unroll
        for (int j = 0; j < 5; ++j)
            cw.q[j] = lds4[T1OFF4 + ox * ACTS4 + 2 * g + j];
        const int oxg = ox0 + ox;
        if (!edge) {
            #pragma unroll
            for (int dv = 0; dv < 4; ++dv) {
                float acc = 0.f;
                #pragma unroll
                for (int k = 0; k < 12; ++k) acc += gr[k] * cw.s[2 * dv + 11 - k];
                op[(oy0 + 4 * g + dv) * 236 + oxg] = acc;
            }
        } else {
            #pragma unroll
            for (int dv = 0; dv < 4; ++dv) {
                float acc = 0.f;
                #pragma unroll
                for (int k = 0; k < 12; ++k) acc += gr[k] * cw.s[2 * dv + 11 - k];
                const int oy = oy0 + 4 * g + dv;
                if (oy < 236 && oxg < 236) op[oy * 236 + oxg] = acc;
            }
        }
    }
}

extern "C" void kernel_launch(void* const* d_in, const int* in_sizes, int n_in,
                              void* d_out, int out_size, void* d_ws, size_t ws_size,
                              hipStream_t stream) {
    const float* x    = (const float*)d_in[0];
    const float* bias = (const float*)d_in[1];
    const float* fup  = (const float*)d_in[2];
    const float* fdn  = (const float*)d_in[3];
    float* out = (float*)d_out;

    dim3 grid(1024 * 64);
    dim3 block(256);
    afa_kernel<<<grid, block, 0, stream>>>(x, bias, fup, fdn, out);
}

// Round 8
// 245.250 us; speedup vs baseline: 1.3168x; 1.1158x over previous
//
#include <hip/hip_runtime.h>

// AliasFreeActivation fused kernel, round 8:
//  - act and t2t stored in LDS as bf16 -> LDS 21760 B -> 6-7 blocks/CU
//    (was 32224 B, capped at 4 blocks)
//  - pack: v_cvt_pk_bf16_f32 (1 instr / 2 vals); unpack: lshl/and (1 op/val)
//  - leaky = 0.6v + 0.4|v| (2 VALU, abs is free input modifier); the *sqrt2
//    moved to D epilogue (linear through both down-convs)
//  - keeps: direct-global A, bias fold, edge fast paths, 256-thread C/D shapes
//
// Math (verified rounds 1-7):
//  A  h-up:   t1[r][u]=sum_t f[k0+4t]*xw[bb-t], u=8ug+du, k0=(du+1)&3,
//             bb=((du+25-k0)>>2)-1, window x cols [2ug,2ug+7]. No bias.
//  B  v-up:   act[v][:]=leaky( sum_t f[k0+4t]*w[bb-t][:] + bc[k0] );
//             v=8vt8+dv (<74), k0=(dv+1)&3, bb=5+((dv+1)>>2), w[m]=t1[2vt8+m].
//  C  h-down: t2t[o][v]=sum_k g[k]*act[v][2o+11-k], o=8otg+i, window
//             act bf16 cols [16otg,16otg+25] = dwords [8otg,8otg+12].
//  D  v-down: out[4g+dv][ox]=sqrt2 * sum_k g[k]*t2t[ox][8g+2dv+11-k],
//             window t2t bf16 cols [8g,8g+17] = dwords [4g,4g+8].
//
// LDS (bytes): act bf16 74x88 @0 (13024) | t1 f32 26x84dw @13024 (8736)
//              t2t bf16 32x88 @13024 (5632, aliases t1, live after C).
//              Total 21760 B.

typedef float f4 __attribute__((ext_vector_type(4)));

#define ACT_SB   176      // act row stride bytes (88 bf16)
#define T1_OFF   13024
#define T1S4     21
#define T2T_SB   176
#define LDS_B    21760

static __device__ __forceinline__ unsigned cvtpk_bf16(float lo, float hi) {
    unsigned r;
    asm("v_cvt_pk_bf16_f32 %0, %1, %2" : "=v"(r) : "v"(lo), "v"(hi));
    return r;
}
static __device__ __forceinline__ float bflo(unsigned d) {
    return __uint_as_float(d << 16);
}
static __device__ __forceinline__ float bfhi(unsigned d) {
    return __uint_as_float(d & 0xffff0000u);
}

__global__ __launch_bounds__(256, 6) void afa_kernel(
    const float* __restrict__ x, const float* __restrict__ bias,
    const float* __restrict__ fup, const float* __restrict__ fdn,
    float* __restrict__ out)
{
    __shared__ __align__(16) unsigned char smem[LDS_B];
    f4* const t14 = (f4*)(smem + T1_OFF);

    const int tid   = threadIdx.x;
    const int blk   = blockIdx.x;
    const int plane = blk >> 6;
    const int tile  = blk & 63;
    const int ty = tile >> 3, tx = tile & 7;
    const bool edge = (tx == 7) || (ty == 7);

    float fr[24], gr[12];
    #pragma unroll
    for (int i = 0; i < 24; ++i) fr[i] = fup[i];
    #pragma unroll
    for (int i = 0; i < 12; ++i) gr[i] = fdn[i];

    // bias fold: up(x+b) = up(x) + b*s[k0u]*s[k0v], s[p]=sum_t f[p+4t]
    const float s0 = fr[0] + fr[4] + fr[8]  + fr[12] + fr[16] + fr[20];
    const float s1 = fr[1] + fr[5] + fr[9]  + fr[13] + fr[17] + fr[21];
    const float s2 = fr[2] + fr[6] + fr[10] + fr[14] + fr[18] + fr[22];
    const float s3 = fr[3] + fr[7] + fr[11] + fr[15] + fr[19] + fr[23];
    const float b  = bias[plane & 255];
    const f4 su4 = {s1, s2, s3, s0};              // s[(cc+1)&3]
    f4 bc[4];
    bc[0] = su4 * (b * s0);
    bc[1] = su4 * (b * s1);
    bc[2] = su4 * (b * s2);
    bc[3] = su4 * (b * s3);

    const int iy_base = 16 * ty + 1;
    const int ix_base = 16 * tx + 1;
    const float* xp = x + (size_t)plane * (128 * 128);

    // ---- A: horizontal upsample, direct global reads -> t1 (26 x 80) ----
    for (int task = tid; task < 260; task += 256) {
        const int r = task / 10, ug = task - r * 10;
        float xw[8];
        if (!edge) {
            const float* row = xp + (iy_base + r) * 128 + (ix_base + 2 * ug);
            #pragma unroll
            for (int m = 0; m < 8; ++m) xw[m] = row[m];
        } else {
            const int iy = min(iy_base + r, 127);
            const float* row = xp + iy * 128;
            const int ix0 = ix_base + 2 * ug;
            #pragma unroll
            for (int m = 0; m < 8; ++m) xw[m] = row[min(ix0 + m, 127)];
        }
        f4 res0, res1;
        #pragma unroll
        for (int du = 0; du < 8; ++du) {
            const int k0 = (du + 1) & 3;
            const int bb = ((du + 25 - k0) >> 2) - 1;
            float acc = 0.f;
            #pragma unroll
            for (int t = 0; t < 6; ++t) acc += fr[k0 + 4 * t] * xw[bb - t];
            if (du < 4) res0[du] = acc; else res1[du - 4] = acc;
        }
        t14[r * T1S4 + 2 * ug]     = res0;
        t14[r * T1S4 + 2 * ug + 1] = res1;
    }
    __syncthreads();

    // ---- B: vertical upsample + bias + leaky -> act bf16 (74 x 76 used) ----
    if (tid < 190) {
        const int vt8 = tid / 19, ut = tid - vt8 * 19;
        f4 w[8];
        #pragma unroll
        for (int m = 0; m < 8; ++m)
            w[m] = t14[(2 * vt8 + m) * T1S4 + ut];
        #pragma unroll
        for (int dv = 0; dv < 8; ++dv) {
            const int row = 8 * vt8 + dv;
            if (row < 74) {
                const int k0 = (dv + 1) & 3;
                const int bb = 5 + ((dv + 1) >> 2);
                f4 acc = bc[k0];
                #pragma unroll
                for (int t = 0; t < 6; ++t) acc += fr[k0 + 4 * t] * w[bb - t];
                float l0 = 0.6f * acc[0] + 0.4f * __builtin_fabsf(acc[0]);
                float l1 = 0.6f * acc[1] + 0.4f * __builtin_fabsf(acc[1]);
                float l2 = 0.6f * acc[2] + 0.4f * __builtin_fabsf(acc[2]);
                float l3 = 0.6f * acc[3] + 0.4f * __builtin_fabsf(acc[3]);
                uint2 pp;
                pp.x = cvtpk_bf16(l0, l1);
                pp.y = cvtpk_bf16(l2, l3);
                *(uint2*)(smem + row * ACT_SB + 8 * ut) = pp;
            }
        }
    }
    __syncthreads();

    // ---- C: horizontal downsample -> t2t bf16 [o][v] (transposed) ----
    {
        // batch 1: rows 0..63, all 256 threads
        const int v = tid & 63, otg = tid >> 6;
        {
            const unsigned* ar = (const unsigned*)(smem + v * ACT_SB + 32 * otg);
            uint4 q0 = *(const uint4*)(ar);
            uint4 q1 = *(const uint4*)(ar + 4);
            uint4 q2 = *(const uint4*)(ar + 8);
            const unsigned dl = ar[12];
            unsigned d[13] = {q0.x,q0.y,q0.z,q0.w, q1.x,q1.y,q1.z,q1.w,
                              q2.x,q2.y,q2.z,q2.w, dl};
            float w[26];
            #pragma unroll
            for (int j = 0; j < 13; ++j) {
                w[2*j] = bflo(d[j]);
                if (2*j + 1 < 26) w[2*j+1] = bfhi(d[j]);
            }
            #pragma unroll
            for (int i = 0; i < 8; ++i) {
                float acc = 0.f;
                #pragma unroll
                for (int k = 0; k < 12; ++k) acc += gr[k] * w[2*i + 11 - k];
                unsigned p = cvtpk_bf16(acc, acc);
                *(unsigned short*)(smem + T1_OFF + (8*otg + i) * T2T_SB + 2*v)
                    = (unsigned short)p;
            }
        }
        // batch 2: rows 64..73
        if (tid < 64) {
            const int otg2 = tid >> 4, vr = tid & 15;
            if (vr < 10) {
                const int v2 = 64 + vr;
                const unsigned* ar = (const unsigned*)(smem + v2 * ACT_SB + 32 * otg2);
                uint4 q0 = *(const uint4*)(ar);
                uint4 q1 = *(const uint4*)(ar + 4);
                uint4 q2 = *(const uint4*)(ar + 8);
                const unsigned dl = ar[12];
                unsigned d[13] = {q0.x,q0.y,q0.z,q0.w, q1.x,q1.y,q1.z,q1.w,
                                  q2.x,q2.y,q2.z,q2.w, dl};
                float w[26];
                #pragma unroll
                for (int j = 0; j < 13; ++j) {
                    w[2*j] = bflo(d[j]);
                    if (2*j + 1 < 26) w[2*j+1] = bfhi(d[j]);
                }
                #pragma unroll
                for (int i = 0; i < 8; ++i) {
                    float acc = 0.f;
                    #pragma unroll
                    for (int k = 0; k < 12; ++k) acc += gr[k] * w[2*i + 11 - k];
                    unsigned p = cvtpk_bf16(acc, acc);
                    *(unsigned short*)(smem + T1_OFF + (8*otg2 + i) * T2T_SB + 2*v2)
                        = (unsigned short)p;
                }
            }
        }
    }
    __syncthreads();

    // ---- D: vertical downsample from t2t bf16, *sqrt2, store to global ----
    {
        const int oy0 = ty * 32, ox0 = tx * 32;
        float* op = out + (size_t)plane * (236 * 236);
        const int ox = tid & 31, g = tid >> 5;
        const unsigned* tr = (const unsigned*)(smem + T1_OFF + ox * T2T_SB + 16 * g);
        uint4 q0 = *(const uint4*)(tr);
        uint4 q1 = *(const uint4*)(tr + 4);
        const unsigned dl = tr[8];
        unsigned d[9] = {q0.x,q0.y,q0.z,q0.w, q1.x,q1.y,q1.z,q1.w, dl};
        float cw[18];
        #pragma unroll
        for (int j = 0; j < 9; ++j) {
            cw[2*j]   = bflo(d[j]);
            cw[2*j+1] = bfhi(d[j]);
        }
        const int oxg = ox0 + ox;
        if (!edge) {
            #pragma unroll
            for (int dv = 0; dv < 4; ++dv) {
                float acc = 0.f;
                #pragma unroll
                for (int k = 0; k < 12; ++k) acc += gr[k] * cw[2*dv + 11 - k];
                op[(oy0 + 4 * g + dv) * 236 + oxg] = acc * 1.4142135623730951f;
            }
        } else {
            #pragma unroll
            for (int dv = 0; dv < 4; ++dv) {
                float acc = 0.f;
                #pragma unroll
                for (int k = 0; k < 12; ++k) acc += gr[k] * cw[2*dv + 11 - k];
                const int oy = oy0 + 4 * g + dv;
                if (oy < 236 && oxg < 236)
                    op[oy * 236 + oxg] = acc * 1.4142135623730951f;
            }
        }
    }
}

extern "C" void kernel_launch(void* const* d_in, const int* in_sizes, int n_in,
                              void* d_out, int out_size, void* d_ws, size_t ws_size,
                              hipStream_t stream) {
    const float* x    = (const float*)d_in[0];
    const float* bias = (const float*)d_in[1];
    const float* fup  = (const float*)d_in[2];
    const float* fdn  = (const float*)d_in[3];
    float* out = (float*)d_out;

    dim3 grid(1024 * 64);
    dim3 block(256);
    afa_kernel<<<grid, block, 0, stream>>>(x, bias, fup, fdn, out);
}

// Round 10
// 227.830 us; speedup vs baseline: 1.4175x; 1.0765x over previous
//
#include <hip/hip_runtime.h>

// AliasFreeActivation fused kernel, round 10 (= r9 with cvt_pkrtz type fix):
//  - act/t2t stored as f16; C and D convolutions via v_dot2_f32_f16
//    (__builtin_amdgcn_fdot2): 6 dot2 per output, NO unpack ops
//  - B math on float2 to enable v_pk_fma_f32 selection (gfx90a+ packed f32)
//  - keeps r8: direct-global A, bias fold, edge fast paths, 21.8KB LDS,
//    launch_bounds(256,6), sqrt2 folded into D epilogue
//
// Math (verified rounds 1-8):
//  A  h-up:   t1[r][u]=sum_t f[k0+4t]*xw[bb-t], u=8ug+du, k0=(du+1)&3,
//             bb=((du+25-k0)>>2)-1, window x cols [2ug,2ug+7]. No bias.
//  B  v-up:   act[v][:]=leaky( sum_t f[k0+4t]*w[bb-t][:] + bc[k0] );
//             v=8vt8+dv (<74), k0=(dv+1)&3, bb=5+((dv+1)>>2), w[m]=t1[2vt8+m].
//  C  h-down: t2t[o][v]=sum_k g[k]*act[v][2o+11-k] = sum_m dot2(actdw[i+m],gpk[m])
//             for o=8otg+i, window dwords [8otg..8otg+12], gpk[m]=(g[11-2m],g[10-2m]).
//  D  v-down: out[4g+dv][ox]=sqrt2*sum_m dot2(t2tdw[dv+m],gpk[m]),
//             window t2t dwords [4g..4g+8].
//
// LDS (bytes): act f16 74x88 @0 (13024) | t1 f32 26x84dw @13024 (8736)
//              t2t f16 32x88 @13024 (5632, aliases t1, live after C).
//              Total 21760 B.

typedef float   f4 __attribute__((ext_vector_type(4)));
typedef float   f2 __attribute__((ext_vector_type(2)));
typedef _Float16 h2 __attribute__((ext_vector_type(2)));

#define ACT_SB   176      // act row stride bytes (88 f16)
#define T1_OFF   13024
#define T1S4     21
#define T2T_SB   176
#define LDS_B    21760

static __device__ __forceinline__ h2 as_h2(unsigned u) {
    union { unsigned u; h2 h; } x; x.u = u; return x.h;
}
static __device__ __forceinline__ unsigned pkrtz_u32(float lo, float hi) {
    union { __fp16 __attribute__((ext_vector_type(2))) h; unsigned u; } x;
    x.h = __builtin_amdgcn_cvt_pkrtz(lo, hi);
    return x.u;
}

__global__ __launch_bounds__(256, 6) void afa_kernel(
    const float* __restrict__ x, const float* __restrict__ bias,
    const float* __restrict__ fup, const float* __restrict__ fdn,
    float* __restrict__ out)
{
    __shared__ __align__(16) unsigned char smem[LDS_B];
    f4* const t14 = (f4*)(smem + T1_OFF);

    const int tid   = threadIdx.x;
    const int blk   = blockIdx.x;
    const int plane = blk >> 6;
    const int tile  = blk & 63;
    const int ty = tile >> 3, tx = tile & 7;
    const bool edge = (tx == 7) || (ty == 7);

    float fr[24], gr[12];
    #pragma unroll
    for (int i = 0; i < 24; ++i) fr[i] = fup[i];
    #pragma unroll
    for (int i = 0; i < 12; ++i) gr[i] = fdn[i];

    // packed reversed filter pairs for dot2: gpk[m] = (g[11-2m], g[10-2m])
    h2 gpk[6];
    #pragma unroll
    for (int m = 0; m < 6; ++m) {
        h2 p;
        p.x = (_Float16)gr[11 - 2 * m];
        p.y = (_Float16)gr[10 - 2 * m];
        gpk[m] = p;
    }

    // bias fold: up(x+b) = up(x) + b*s[k0u]*s[k0v], s[p]=sum_t f[p+4t]
    const float s0 = fr[0] + fr[4] + fr[8]  + fr[12] + fr[16] + fr[20];
    const float s1 = fr[1] + fr[5] + fr[9]  + fr[13] + fr[17] + fr[21];
    const float s2 = fr[2] + fr[6] + fr[10] + fr[14] + fr[18] + fr[22];
    const float s3 = fr[3] + fr[7] + fr[11] + fr[15] + fr[19] + fr[23];
    const float b  = bias[plane & 255];
    const f4 su4 = {s1, s2, s3, s0};              // s[(cc+1)&3]
    f4 bc[4];
    bc[0] = su4 * (b * s0);
    bc[1] = su4 * (b * s1);
    bc[2] = su4 * (b * s2);
    bc[3] = su4 * (b * s3);

    const int iy_base = 16 * ty + 1;
    const int ix_base = 16 * tx + 1;
    const float* xp = x + (size_t)plane * (128 * 128);

    // ---- A: horizontal upsample, direct global reads -> t1 (26 x 80) ----
    for (int task = tid; task < 260; task += 256) {
        const int r = task / 10, ug = task - r * 10;
        float xw[8];
        if (!edge) {
            const float* row = xp + (iy_base + r) * 128 + (ix_base + 2 * ug);
            #pragma unroll
            for (int m = 0; m < 8; ++m) xw[m] = row[m];
        } else {
            const int iy = min(iy_base + r, 127);
            const float* row = xp + iy * 128;
            const int ix0 = ix_base + 2 * ug;
            #pragma unroll
            for (int m = 0; m < 8; ++m) xw[m] = row[min(ix0 + m, 127)];
        }
        f4 res0, res1;
        #pragma unroll
        for (int du = 0; du < 8; ++du) {
            const int k0 = (du + 1) & 3;
            const int bb = ((du + 25 - k0) >> 2) - 1;
            float acc = 0.f;
            #pragma unroll
            for (int t = 0; t < 6; ++t) acc += fr[k0 + 4 * t] * xw[bb - t];
            if (du < 4) res0[du] = acc; else res1[du - 4] = acc;
        }
        t14[r * T1S4 + 2 * ug]     = res0;
        t14[r * T1S4 + 2 * ug + 1] = res1;
    }
    __syncthreads();

    // ---- B: vertical upsample + bias + leaky -> act f16 (74 x 76 used) ----
    if (tid < 190) {
        const int vt8 = tid / 19, ut = tid - vt8 * 19;
        f4 w[8];
        #pragma unroll
        for (int m = 0; m < 8; ++m)
            w[m] = t14[(2 * vt8 + m) * T1S4 + ut];
        f2 wl[8], wh[8];
        #pragma unroll
        for (int m = 0; m < 8; ++m) {
            wl[m] = f2{w[m][0], w[m][1]};
            wh[m] = f2{w[m][2], w[m][3]};
        }
        #pragma unroll
        for (int dv = 0; dv < 8; ++dv) {
            const int row = 8 * vt8 + dv;
            if (row < 74) {
                const int k0 = (dv + 1) & 3;
                const int bb = 5 + ((dv + 1) >> 2);
                f2 al = {bc[k0][0], bc[k0][1]};
                f2 ah = {bc[k0][2], bc[k0][3]};
                #pragma unroll
                for (int t = 0; t < 6; ++t) {
                    al += fr[k0 + 4 * t] * wl[bb - t];
                    ah += fr[k0 + 4 * t] * wh[bb - t];
                }
                float l0 = 0.6f * al[0] + 0.4f * __builtin_fabsf(al[0]);
                float l1 = 0.6f * al[1] + 0.4f * __builtin_fabsf(al[1]);
                float l2 = 0.6f * ah[0] + 0.4f * __builtin_fabsf(ah[0]);
                float l3 = 0.6f * ah[1] + 0.4f * __builtin_fabsf(ah[1]);
                uint2 pp;
                pp.x = pkrtz_u32(l0, l1);
                pp.y = pkrtz_u32(l2, l3);
                *(uint2*)(smem + row * ACT_SB + 8 * ut) = pp;
            }
        }
    }
    __syncthreads();

    // ---- C: horizontal downsample via dot2 -> t2t f16 [o][v] (transposed) ----
    {
        // batch 1: rows 0..63, all 256 threads
        const int v = tid & 63, otg = tid >> 6;
        {
            const unsigned* ar = (const unsigned*)(smem + v * ACT_SB + 32 * otg);
            uint4 q0 = *(const uint4*)(ar);
            uint4 q1 = *(const uint4*)(ar + 4);
            uint4 q2 = *(const uint4*)(ar + 8);
            const unsigned dl = ar[12];
            unsigned d[13] = {q0.x,q0.y,q0.z,q0.w, q1.x,q1.y,q1.z,q1.w,
                              q2.x,q2.y,q2.z,q2.w, dl};
            #pragma unroll
            for (int i = 0; i < 8; ++i) {
                float acc = 0.f;
                #pragma unroll
                for (int m = 0; m < 6; ++m)
                    acc = __builtin_amdgcn_fdot2(as_h2(d[i + m]), gpk[m], acc, false);
                _Float16 hv = (_Float16)acc;
                *(_Float16*)(smem + T1_OFF + (8*otg + i) * T2T_SB + 2*v) = hv;
            }
        }
        // batch 2: rows 64..73
        if (tid < 64) {
            const int otg2 = tid >> 4, vr = tid & 15;
            if (vr < 10) {
                const int v2 = 64 + vr;
                const unsigned* ar = (const unsigned*)(smem + v2 * ACT_SB + 32 * otg2);
                uint4 q0 = *(const uint4*)(ar);
                uint4 q1 = *(const uint4*)(ar + 4);
                uint4 q2 = *(const uint4*)(ar + 8);
                const unsigned dl = ar[12];
                unsigned d[13] = {q0.x,q0.y,q0.z,q0.w, q1.x,q1.y,q1.z,q1.w,
                                  q2.x,q2.y,q2.z,q2.w, dl};
                #pragma unroll
                for (int i = 0; i < 8; ++i) {
                    float acc = 0.f;
                    #pragma unroll
                    for (int m = 0; m < 6; ++m)
                        acc = __builtin_amdgcn_fdot2(as_h2(d[i + m]), gpk[m], acc, false);
                    _Float16 hv = (_Float16)acc;
                    *(_Float16*)(smem + T1_OFF + (8*otg2 + i) * T2T_SB + 2*v2) = hv;
                }
            }
        }
    }
    __syncthreads();

    // ---- D: vertical downsample via dot2, *sqrt2, store to global ----
    {
        const int oy0 = ty * 32, ox0 = tx * 32;
        float* op = out + (size_t)plane * (236 * 236);
        const int ox = tid & 31, g = tid >> 5;
        const unsigned* tr = (const unsigned*)(smem + T1_OFF + ox * T2T_SB + 16 * g);
        uint4 q0 = *(const uint4*)(tr);
        uint4 q1 = *(const uint4*)(tr + 4);
        const unsigned dl = tr[8];
        unsigned d[9] = {q0.x,q0.y,q0.z,q0.w, q1.x,q1.y,q1.z,q1.w, dl};
        const int oxg = ox0 + ox;
        if (!edge) {
            #pragma unroll
            for (int dv = 0; dv < 4; ++dv) {
                float acc = 0.f;
                #pragma unroll
                for (int m = 0; m < 6; ++m)
                    acc = __builtin_amdgcn_fdot2(as_h2(d[dv + m]), gpk[m], acc, false);
                op[(oy0 + 4 * g + dv) * 236 + oxg] = acc * 1.4142135623730951f;
            }
        } else {
            #pragma unroll
            for (int dv = 0; dv < 4; ++dv) {
                float acc = 0.f;
                #pragma unroll
                for (int m = 0; m < 6; ++m)
                    acc = __builtin_amdgcn_fdot2(as_h2(d[dv + m]), gpk[m], acc, false);
                const int oy = oy0 + 4 * g + dv;
                if (oy < 236 && oxg < 236)
                    op[oy * 236 + oxg] = acc * 1.4142135623730951f;
            }
        }
    }
}

extern "C" void kernel_launch(void* const* d_in, const int* in_sizes, int n_in,
                              void* d_out, int out_size, void* d_ws, size_t ws_size,
                              hipStream_t stream) {
    const float* x    = (const float*)d_in[0];
    const float* bias = (const float*)d_in[1];
    const float* fup  = (const float*)d_in[2];
    const float* fdn  = (const float*)d_in[3];
    float* out = (float*)d_out;

    dim3 grid(1024 * 64);
    dim3 block(256);
    afa_kernel<<<grid, block, 0, stream>>>(x, bias, fup, fdn, out);
}